// Round 1
// baseline (671.727 us; speedup 1.0000x reference)
//
#include <hip/hip_runtime.h>

#define NN 8000
#define NPP 1000
#define BBATCH 8
#define FF 1000
#define HCC 32
#define KK 5
#define EE 80000
#define TRIN 499500
#define HID 128
#define EPSV 1e-5f

// workspace layout (units: 4-byte elements)
#define IDX_DEGI 0
#define IDX_CNT 8000
#define IDX_FILL 16000
#define IDX_ROWS 24000
#define IDX_DINV 33024
#define IDX_CSRC 41024
#define IDX_CSRW 121024
#define IDX_ACC  201024
#define IDX_EMB  202048
#define IDX_CK   204800
#define CKSTRIDE 256000
#define IDX_BA   1484800
#define IDX_BB   1740800
#define IDX_BC   1996800
#define IDX_H1   2252800
#define IDX_H2   2508800
#define IDX_H3   2764800

// ---------------- graph preprocessing ----------------

__global__ void k_count(const int* __restrict__ src, const int* __restrict__ dst,
                        int* __restrict__ degi, int* __restrict__ cnt) {
  int e = blockIdx.x * blockDim.x + threadIdx.x;
  if (e >= EE) return;
  atomicAdd(&degi[src[e]], 1);
  atomicAdd(&cnt[dst[e]], 1);
}

__global__ void k_dinv(const int* __restrict__ degi, float* __restrict__ dinv) {
  int i = blockIdx.x * blockDim.x + threadIdx.x;
  if (i >= NN) return;
  int d = degi[i];
  dinv[i] = (d > 0) ? (1.0f / sqrtf((float)d)) : 0.0f;
}

__global__ void k_scan(const int* __restrict__ cnt, int* __restrict__ rows) {
  __shared__ int ssum[1024];
  int tid = threadIdx.x;
  int base = tid * 8;
  int loc[8];
  int s = 0;
#pragma unroll
  for (int q = 0; q < 8; ++q) {
    int idx = base + q;
    int v = (idx < NN) ? cnt[idx] : 0;
    loc[q] = s;
    s += v;
  }
  ssum[tid] = s;
  __syncthreads();
  for (int d = 1; d < 1024; d <<= 1) {
    int v = (tid >= d) ? ssum[tid - d] : 0;
    __syncthreads();
    ssum[tid] += v;
    __syncthreads();
  }
  int off = (tid == 0) ? 0 : ssum[tid - 1];
#pragma unroll
  for (int q = 0; q < 8; ++q) {
    int idx = base + q;
    if (idx < NN) rows[idx] = off + loc[q];
  }
  if (tid == 1023) rows[NN] = ssum[1023];
}

__global__ void k_fill(const int* __restrict__ src, const int* __restrict__ dst,
                       const float* __restrict__ dinv, const int* __restrict__ rows,
                       int* __restrict__ fill, int* __restrict__ csrc,
                       float* __restrict__ csw) {
  int e = blockIdx.x * blockDim.x + threadIdx.x;
  if (e >= EE) return;
  int s = src[e], d = dst[e];
  int pos = rows[d] + atomicAdd(&fill[d], 1);
  csrc[pos] = s;
  csw[pos] = -dinv[s] * dinv[d];
}

// ---------------- Chebyshev (Clenshaw) ----------------

// layer-1 coefficient matrices: ck[k][i,:] = W0[k][i % 1000, :]
__global__ void k_tile(const float* __restrict__ w0, float* __restrict__ ckbuf) {
  int idx = blockIdx.x * 256 + threadIdx.x;  // grid 5000 -> 1,280,000 exact
  int k = idx / CKSTRIDE;
  int rem = idx % CKSTRIDE;
  int i = rem / HCC;
  int c = rem % HCC;
  ckbuf[idx] = w0[k * (FF * HCC) + (i % NPP) * HCC + c];
}

// layer-2/3 coefficients: ck[k] = h @ W[k]   (W: (K,32,32))
__global__ void __launch_bounds__(256) k_ck(const float* __restrict__ h,
                                            const float* __restrict__ W,
                                            float* __restrict__ ckbuf) {
  __shared__ float Ws[KK * HCC * HCC];
  __shared__ float hs[8][HCC];
  int tid = threadIdx.x;
  for (int i = tid; i < KK * HCC * HCC; i += 256) Ws[i] = W[i];
  int c = tid & 31, r = tid >> 5;
  int row = blockIdx.x * 8 + r;
  hs[r][c] = h[row * HCC + c];
  __syncthreads();
#pragma unroll
  for (int k = 0; k < KK; ++k) {
    float acc = 0.0f;
#pragma unroll
    for (int j = 0; j < HCC; ++j) acc += hs[r][j] * Ws[k * (HCC * HCC) + j * HCC + c];
    ckbuf[k * CKSTRIDE + row * HCC + c] = acc;
  }
}

// out[d,:] = alpha * sum_{e: dst=d} w_e * in[src_e,:] + beta*prev[d,:] + ck[d,:] (+bias, tanh)
__global__ void __launch_bounds__(256) k_prop(
    const float* __restrict__ in, const float* __restrict__ prev,
    const float* __restrict__ ck, float* __restrict__ out,
    const int* __restrict__ rows, const int* __restrict__ csrc,
    const float* __restrict__ csw, float alpha, float beta,
    const float* __restrict__ bias, int do_tanh) {
  int tid = threadIdx.x;
  int c = tid & 31, r = tid >> 5;
  int row = blockIdx.x * 8 + r;
  int s = rows[row], e = rows[row + 1];
  float acc = 0.0f;
  for (int i = s; i < e; ++i) acc += csw[i] * in[csrc[i] * HCC + c];
  float v = alpha * acc + beta * prev[row * HCC + c] + ck[row * HCC + c];
  if (bias) v += bias[c];
  if (do_tanh) v = tanhf(v);
  out[row * HCC + c] = v;
}

// ---------------- pooling + hbn ----------------

__global__ void __launch_bounds__(256) k_pool(const float* __restrict__ h1,
                                              const float* __restrict__ h2,
                                              const float* __restrict__ h3,
                                              float* __restrict__ emb) {
  int bx = blockIdx.x;
  int g = bx / 3, L = bx % 3;
  const float* h = (L == 0) ? h1 : ((L == 1) ? h2 : h3);
  __shared__ float red[8][32];
  int tid = threadIdx.x;
  int c = tid & 31, grp = tid >> 5;
  float s = 0.0f;
  for (int n = grp; n < NPP; n += 8) s += h[((size_t)g * NPP + n) * HCC + c];
  red[grp][c] = s;
  __syncthreads();
  if (grp == 0) {
    float t = 0.0f;
#pragma unroll
    for (int q = 0; q < 8; ++q) t += red[q][c];
    emb[g * 96 + L * 32 + c] = t * (1.0f / (float)NPP);
  }
}

__global__ void k_hbn(const float* __restrict__ emb, const float* __restrict__ gg,
                      const float* __restrict__ bb, float* __restrict__ out) {
  int col = threadIdx.x;
  if (col >= 96) return;
  float v[8];
  float m = 0.0f;
#pragma unroll
  for (int q = 0; q < 8; ++q) { v[q] = emb[q * 96 + col]; m += v[q]; }
  m *= 0.125f;
  float va = 0.0f;
#pragma unroll
  for (int q = 0; q < 8; ++q) { float d = v[q] - m; va += d * d; }
  va *= 0.125f;
  float s = gg[col] * rsqrtf(va + EPSV);
  float t = bb[col] - m * s;
#pragma unroll
  for (int q = 0; q < 8; ++q) out[16 + q * 96 + col] = s * v[q] + t;
}

// ---------------- big GEMM: fbn @ mlp_w1 ----------------

__device__ __forceinline__ long long tri_S(int i) {
  return (long long)i * (FF - 1) - ((long long)i * (i - 1)) / 2;
}

__global__ void __launch_bounds__(128) k_gemm1(const float* __restrict__ x,
                                               const float* __restrict__ bng,
                                               const float* __restrict__ bnb,
                                               const float* __restrict__ W1,
                                               float* __restrict__ accg) {
  __shared__ float fbn_s[128][8];
  const int tid = threadIdx.x;
  const int GJ = 512;
  int j0 = blockIdx.x * GJ;
  float acc[8] = {0, 0, 0, 0, 0, 0, 0, 0};
  for (int jt = j0; jt < j0 + GJ && jt < TRIN; jt += 128) {
    int j = jt + tid;
    float vals[8];
    if (j < TRIN) {
      double t = (double)(2 * FF - 1);
      int i = (int)((t - sqrt(t * t - 8.0 * (double)j)) * 0.5);
      if (i < 0) i = 0;
      if (i > FF - 2) i = FF - 2;
      while (tri_S(i + 1) <= (long long)j) ++i;
      while (tri_S(i) > (long long)j) --i;
      int i1 = j - (int)tri_S(i) + i + 1;
      size_t base = (size_t)i * FF + i1;
#pragma unroll
      for (int b = 0; b < 8; ++b) vals[b] = x[(size_t)b * (FF * NPP) + base];
      float m = 0.0f;
#pragma unroll
      for (int b = 0; b < 8; ++b) m += vals[b];
      m *= 0.125f;
      float va = 0.0f;
#pragma unroll
      for (int b = 0; b < 8; ++b) { float d = vals[b] - m; va += d * d; }
      va *= 0.125f;
      float s = bng[j] * rsqrtf(va + EPSV);
      float tt = bnb[j] - m * s;
#pragma unroll
      for (int b = 0; b < 8; ++b) vals[b] = s * vals[b] + tt;
    } else {
#pragma unroll
      for (int b = 0; b < 8; ++b) vals[b] = 0.0f;
    }
    __syncthreads();
    *(float4*)&fbn_s[tid][0] = make_float4(vals[0], vals[1], vals[2], vals[3]);
    *(float4*)&fbn_s[tid][4] = make_float4(vals[4], vals[5], vals[6], vals[7]);
    __syncthreads();
    int jmax = min(128, TRIN - jt);
    const float* wp = W1 + (size_t)jt * HID + tid;
#pragma unroll 4
    for (int jj = 0; jj < jmax; ++jj) {
      float wv = wp[(size_t)jj * HID];
      float4 f0 = *(const float4*)&fbn_s[jj][0];
      float4 f1 = *(const float4*)&fbn_s[jj][4];
      acc[0] += f0.x * wv; acc[1] += f0.y * wv;
      acc[2] += f0.z * wv; acc[3] += f0.w * wv;
      acc[4] += f1.x * wv; acc[5] += f1.y * wv;
      acc[6] += f1.z * wv; acc[7] += f1.w * wv;
    }
  }
#pragma unroll
  for (int b = 0; b < 8; ++b) atomicAdd(&accg[b * HID + tid], acc[b]);
}

// ---------------- MLP tail ----------------

__global__ void __launch_bounds__(128) k_mlp(
    const float* __restrict__ acc, const float* __restrict__ mb1,
    const float* __restrict__ g1, const float* __restrict__ be1,
    const float* __restrict__ W2, const float* __restrict__ mb2,
    const float* __restrict__ g2, const float* __restrict__ be2,
    const float* __restrict__ W3, const float* __restrict__ mb3,
    const float* __restrict__ g3, const float* __restrict__ be3,
    const float* __restrict__ W4, const float* __restrict__ mb4,
    float* __restrict__ out) {
  __shared__ float A[8][128];
  __shared__ float Bm[8][64];
  __shared__ float Cm[8][64];
  __shared__ float lg[8][2];
  int tid = threadIdx.x;
  if (tid < 128) {
    float v[8];
#pragma unroll
    for (int b = 0; b < 8; ++b) v[b] = acc[b * HID + tid] + mb1[tid];
    float m = 0.0f;
#pragma unroll
    for (int b = 0; b < 8; ++b) m += v[b];
    m *= 0.125f;
    float va = 0.0f;
#pragma unroll
    for (int b = 0; b < 8; ++b) { float d = v[b] - m; va += d * d; }
    va *= 0.125f;
    float s = g1[tid] * rsqrtf(va + EPSV);
    float t = be1[tid] - m * s;
#pragma unroll
    for (int b = 0; b < 8; ++b) {
      float z = s * v[b] + t;
      A[b][tid] = (z > 0.0f) ? z : 0.0f;
    }
  }
  __syncthreads();
  if (tid < 64) {
    float v[8];
#pragma unroll
    for (int b = 0; b < 8; ++b) {
      float a2 = mb2[tid];
      for (int j = 0; j < 128; ++j) a2 += A[b][j] * W2[j * 64 + tid];
      v[b] = a2;
    }
    float m = 0.0f;
#pragma unroll
    for (int b = 0; b < 8; ++b) m += v[b];
    m *= 0.125f;
    float va = 0.0f;
#pragma unroll
    for (int b = 0; b < 8; ++b) { float d = v[b] - m; va += d * d; }
    va *= 0.125f;
    float s = g2[tid] * rsqrtf(va + EPSV);
    float t = be2[tid] - m * s;
#pragma unroll
    for (int b = 0; b < 8; ++b) {
      float z = s * v[b] + t;
      Bm[b][tid] = (z > 0.0f) ? z : 0.0f;
    }
  }
  __syncthreads();
  if (tid < 64) {
    float v[8];
#pragma unroll
    for (int b = 0; b < 8; ++b) {
      float a3 = mb3[tid];
      for (int j = 0; j < 64; ++j) a3 += Bm[b][j] * W3[j * 64 + tid];
      v[b] = a3;
    }
    float m = 0.0f;
#pragma unroll
    for (int b = 0; b < 8; ++b) m += v[b];
    m *= 0.125f;
    float va = 0.0f;
#pragma unroll
    for (int b = 0; b < 8; ++b) { float d = v[b] - m; va += d * d; }
    va *= 0.125f;
    float s = g3[tid] * rsqrtf(va + EPSV);
    float t = be3[tid] - m * s;
#pragma unroll
    for (int b = 0; b < 8; ++b) {
      float z = s * v[b] + t;
      Cm[b][tid] = (z > 0.0f) ? z : 0.0f;
    }
  }
  __syncthreads();
  if (tid < 16) {
    int b = tid >> 1, c = tid & 1;
    float a4 = mb4[c];
    for (int j = 0; j < 64; ++j) a4 += Cm[b][j] * W4[j * 2 + c];
    lg[b][c] = a4;
  }
  __syncthreads();
  if (tid < 8) {
    float l0 = lg[tid][0], l1 = lg[tid][1];
    float mm = fmaxf(l0, l1);
    float lse = mm + logf(expf(l0 - mm) + expf(l1 - mm));
    out[tid * 2 + 0] = l0 - lse;
    out[tid * 2 + 1] = l1 - lse;
  }
}

// ---------------- launch ----------------

extern "C" void kernel_launch(void* const* d_in, const int* in_sizes, int n_in,
                              void* d_out, int out_size, void* d_ws, size_t ws_size,
                              hipStream_t stream) {
  const float* x = (const float*)d_in[0];
  const int* ei = (const int*)d_in[1];
  const int* src = ei;
  const int* dst = ei + EE;
  const float* cw0 = (const float*)d_in[3];
  const float* cb0 = (const float*)d_in[4];
  const float* cw1 = (const float*)d_in[5];
  const float* cb1 = (const float*)d_in[6];
  const float* cw2 = (const float*)d_in[7];
  const float* cb2 = (const float*)d_in[8];
  const float* bnhg = (const float*)d_in[9];
  const float* bnhb = (const float*)d_in[10];
  const float* bng = (const float*)d_in[11];
  const float* bnb = (const float*)d_in[12];
  const float* mw1 = (const float*)d_in[13];
  const float* mb1 = (const float*)d_in[14];
  const float* b1g = (const float*)d_in[15];
  const float* b1b = (const float*)d_in[16];
  const float* mw2 = (const float*)d_in[17];
  const float* mb2 = (const float*)d_in[18];
  const float* b2g = (const float*)d_in[19];
  const float* b2b = (const float*)d_in[20];
  const float* mw3 = (const float*)d_in[21];
  const float* mb3 = (const float*)d_in[22];
  const float* b3g = (const float*)d_in[23];
  const float* b3b = (const float*)d_in[24];
  const float* mw4 = (const float*)d_in[25];
  const float* mb4 = (const float*)d_in[26];

  float* ws = (float*)d_ws;
  int* wsi = (int*)d_ws;
  float* out = (float*)d_out;

  hipMemsetAsync(wsi + IDX_DEGI, 0, 24000 * sizeof(int), stream);
  hipMemsetAsync(ws + IDX_ACC, 0, 1024 * sizeof(float), stream);

  // big memory-bound GEMM first
  k_gemm1<<<(TRIN + 511) / 512, 128, 0, stream>>>(x, bng, bnb, mw1, ws + IDX_ACC);

  k_count<<<(EE + 255) / 256, 256, 0, stream>>>(src, dst, wsi + IDX_DEGI, wsi + IDX_CNT);
  k_dinv<<<(NN + 255) / 256, 256, 0, stream>>>(wsi + IDX_DEGI, ws + IDX_DINV);
  k_scan<<<1, 1024, 0, stream>>>(wsi + IDX_CNT, wsi + IDX_ROWS);
  k_fill<<<(EE + 255) / 256, 256, 0, stream>>>(src, dst, ws + IDX_DINV, wsi + IDX_ROWS,
                                               wsi + IDX_FILL, wsi + IDX_CSRC, ws + IDX_CSRW);

  float* ck = ws + IDX_CK;
  float* bA = ws + IDX_BA;
  float* bB = ws + IDX_BB;
  float* bC = ws + IDX_BC;
  float* h1 = ws + IDX_H1;
  float* h2 = ws + IDX_H2;
  float* h3 = ws + IDX_H3;
  const int* rows = wsi + IDX_ROWS;
  const int* csrc = wsi + IDX_CSRC;
  const float* csw = ws + IDX_CSRW;

  auto prop = [&](const float* in, const float* prev, const float* ckp, float* outp,
                  float alpha, float beta, const float* bias, int dt) {
    k_prop<<<NN / 8, 256, 0, stream>>>(in, prev, ckp, outp, rows, csrc, csw,
                                       alpha, beta, bias, dt);
  };

  // layer 1 (Clenshaw; c_k = tiled W0[k])
  k_tile<<<5000, 256, 0, stream>>>(cw0, ck);
  prop(ck + 4 * CKSTRIDE, ck, ck + 3 * CKSTRIDE, bA, 2.0f, 0.0f, nullptr, 0);
  prop(bA, ck + 4 * CKSTRIDE, ck + 2 * CKSTRIDE, bB, 2.0f, -1.0f, nullptr, 0);
  prop(bB, bA, ck + 1 * CKSTRIDE, bC, 2.0f, -1.0f, nullptr, 0);
  prop(bC, bB, ck, h1, 1.0f, -1.0f, cb0, 1);

  // layer 2
  k_ck<<<NN / 8, 256, 0, stream>>>(h1, cw1, ck);
  prop(ck + 4 * CKSTRIDE, ck, ck + 3 * CKSTRIDE, bA, 2.0f, 0.0f, nullptr, 0);
  prop(bA, ck + 4 * CKSTRIDE, ck + 2 * CKSTRIDE, bB, 2.0f, -1.0f, nullptr, 0);
  prop(bB, bA, ck + 1 * CKSTRIDE, bC, 2.0f, -1.0f, nullptr, 0);
  prop(bC, bB, ck, h2, 1.0f, -1.0f, cb1, 1);

  // layer 3
  k_ck<<<NN / 8, 256, 0, stream>>>(h2, cw2, ck);
  prop(ck + 4 * CKSTRIDE, ck, ck + 3 * CKSTRIDE, bA, 2.0f, 0.0f, nullptr, 0);
  prop(bA, ck + 4 * CKSTRIDE, ck + 2 * CKSTRIDE, bB, 2.0f, -1.0f, nullptr, 0);
  prop(bB, bA, ck + 1 * CKSTRIDE, bC, 2.0f, -1.0f, nullptr, 0);
  prop(bC, bB, ck, h3, 1.0f, -1.0f, cb2, 1);

  k_pool<<<24, 256, 0, stream>>>(h1, h2, h3, ws + IDX_EMB);
  k_hbn<<<1, 128, 0, stream>>>(ws + IDX_EMB, bnhg, bnhb, out);
  k_mlp<<<1, 128, 0, stream>>>(ws + IDX_ACC, mb1, b1g, b1b, mw2, mb2, b2g, b2b,
                               mw3, mb3, b3g, b3b, mw4, mb4, out);
}

// Round 2
// 603.714 us; speedup vs baseline: 1.1127x; 1.1127x over previous
//
#include <hip/hip_runtime.h>

#define NN 8000
#define NPP 1000
#define FF 1000
#define HCC 32
#define KK 5
#define EE 80000
#define TRIN 499500
#define HID 128
#define EPSV 1e-5f

// workspace layout (4-byte units)
#define IDX_DEGI 0
#define IDX_CNT  8000
#define IDX_FILL 16000
#define IDX_ACC  24000   // 8 replicas x 1024 fp32
#define IDX_EMB  32192   // 768 fp32
#define ZERO_N   32960   // everything above must start zeroed
#define IDX_ROWS 33024   // 8001 ints
#define IDX_CSRC 41472   // 80000 ints (LOCAL src ids)
#define IDX_CSRW 121472  // 80000 fp32
#define IDX_CK   201472  // 5 x CKSTRIDE
#define CKSTRIDE 256000
#define IDX_BA   1481472
#define IDX_BB   1737472
#define IDX_BC   1993472

// ---------------- graph preprocessing ----------------

__global__ void k_count(const int* __restrict__ src, const int* __restrict__ dst,
                        int* __restrict__ degi, int* __restrict__ cnt) {
  int e = blockIdx.x * blockDim.x + threadIdx.x;
  if (e >= EE) return;
  atomicAdd(&degi[src[e]], 1);
  atomicAdd(&cnt[dst[e]], 1);
}

__global__ void k_scan(const int* __restrict__ cnt, int* __restrict__ rows) {
  __shared__ int ssum[1024];
  int tid = threadIdx.x;
  int base = tid * 8;
  int loc[8];
  int s = 0;
#pragma unroll
  for (int q = 0; q < 8; ++q) {
    int idx = base + q;
    int v = (idx < NN) ? cnt[idx] : 0;
    loc[q] = s;
    s += v;
  }
  ssum[tid] = s;
  __syncthreads();
  for (int d = 1; d < 1024; d <<= 1) {
    int v = (tid >= d) ? ssum[tid - d] : 0;
    __syncthreads();
    ssum[tid] += v;
    __syncthreads();
  }
  int off = (tid == 0) ? 0 : ssum[tid - 1];
#pragma unroll
  for (int q = 0; q < 8; ++q) {
    int idx = base + q;
    if (idx < NN) rows[idx] = off + loc[q];
  }
  if (tid == 1023) rows[NN] = ssum[1023];
}

// fill CSR; computes edge weight from degrees inline (k_dinv folded in);
// stores LOCAL (per-graph) src index.
__global__ void k_fill(const int* __restrict__ src, const int* __restrict__ dst,
                       const int* __restrict__ degi, const int* __restrict__ rows,
                       int* __restrict__ fill, int* __restrict__ csrc,
                       float* __restrict__ csw) {
  int e = blockIdx.x * blockDim.x + threadIdx.x;
  if (e >= EE) return;
  int s = src[e], d = dst[e];
  int pos = rows[d] + atomicAdd(&fill[d], 1);
  int dd = degi[d];
  float w = -rsqrtf((float)degi[s]) * ((dd > 0) ? rsqrtf((float)dd) : 0.0f);
  csrc[pos] = s % NPP;  // local id; block's graph base added at gather time
  csw[pos] = w;
}

// ---------------- Chebyshev (Clenshaw) ----------------

// out[row,:] = alpha * sum_e w_e * in[src_e,:] + beta*prev[row,:] + ck[row,:]
// *_tiled: buffer has NPP rows shared by all graphs (layer-1 W0 coefficients).
__global__ void __launch_bounds__(256) k_prop(
    const float* __restrict__ in, int in_tiled,
    const float* __restrict__ prev, int prev_tiled,
    const float* __restrict__ ck, int ck_tiled,
    float* __restrict__ out,
    const int* __restrict__ rows, const int* __restrict__ csrc,
    const float* __restrict__ csw, float alpha, float beta) {
  const int tid = threadIdx.x;
  const int c = tid & 31, r = tid >> 5;
  const int row = blockIdx.x * 8 + r;
  const int g = blockIdx.x / 125;  // 125 blocks per graph
  const int rl = row - g * NPP;
  const int s = rows[row], e = rows[row + 1];
  const float* inb = in + (in_tiled ? 0 : (size_t)g * NPP * HCC);
  float acc = 0.0f;
  for (int i = s; i < e; ++i) acc += csw[i] * inb[csrc[i] * HCC + c];
  float pv = 0.0f;
  if (prev) pv = prev[(size_t)(prev_tiled ? rl : row) * HCC + c];
  float cv = ck[(size_t)(ck_tiled ? rl : row) * HCC + c];
  out[(size_t)row * HCC + c] = alpha * acc + beta * pv + cv;
}

// final Clenshaw step of a layer (alpha=1, beta=-1) + bias + tanh, fused with:
//  - partial mean-pool into emb (atomicAdd)
//  - next layer's coefficient GEMM ck[k] = h @ Wnext[k]  (h stays in LDS;
//    h is never written to global memory at all)
__global__ void __launch_bounds__(256) k_prop_final(
    const float* __restrict__ in, const float* __restrict__ prev,
    const float* __restrict__ ck, int ck_tiled,
    const int* __restrict__ rows, const int* __restrict__ csrc,
    const float* __restrict__ csw, const float* __restrict__ bias,
    const float* __restrict__ Wnext, float* __restrict__ ckout,
    float* __restrict__ emb, int L) {
  __shared__ float hs[8][HCC];
  __shared__ float Ws[KK * HCC * HCC];
  const int tid = threadIdx.x;
  const int c = tid & 31, r = tid >> 5;
  const int row = blockIdx.x * 8 + r;
  const int g = blockIdx.x / 125;
  const int rl = row - g * NPP;
  if (Wnext) {
    for (int i = tid; i < KK * HCC * HCC; i += 256) Ws[i] = Wnext[i];
  }
  const int s = rows[row], e = rows[row + 1];
  const float* inb = in + (size_t)g * NPP * HCC;
  float acc = 0.0f;
  for (int i = s; i < e; ++i) acc += csw[i] * inb[csrc[i] * HCC + c];
  float pv = prev[(size_t)row * HCC + c];
  float cv = ck[(size_t)(ck_tiled ? rl : row) * HCC + c];
  float v = tanhf(acc - pv + cv + bias[c]);
  hs[r][c] = v;
  __syncthreads();
  if (r == 0) {
    float sum = 0.0f;
#pragma unroll
    for (int q = 0; q < 8; ++q) sum += hs[q][c];
    atomicAdd(&emb[g * 96 + L * HCC + c], sum * (1.0f / (float)NPP));
  }
  if (Wnext) {
#pragma unroll
    for (int k = 0; k < KK; ++k) {
      float a = 0.0f;
#pragma unroll
      for (int jj = 0; jj < HCC; ++jj)
        a += hs[r][jj] * Ws[k * (HCC * HCC) + jj * HCC + c];
      ckout[(size_t)k * CKSTRIDE + (size_t)row * HCC + c] = a;
    }
  }
}

// ---------------- big GEMM: fbn @ mlp_w1 (255.7 MB W1 stream) ----------------

__device__ __forceinline__ int tri_S(int i) { return i * 999 - (i * (i - 1)) / 2; }

__global__ void __launch_bounds__(256) k_gemm1(const float* __restrict__ x,
                                               const float* __restrict__ bng,
                                               const float* __restrict__ bnb,
                                               const float* __restrict__ W1,
                                               float* __restrict__ accrep) {
  __shared__ float fbn_s[256][8];
  __shared__ float red[8][128];
  const int tid = threadIdx.x;
  const int c4 = (tid & 31) * 4;
  const int stripe = tid >> 5;
  float acc[8][4];
#pragma unroll
  for (int b = 0; b < 8; ++b)
#pragma unroll
    for (int q = 0; q < 4; ++q) acc[b][q] = 0.0f;

  for (int t = 0; t < 2; ++t) {
    const int j0 = blockIdx.x * 512 + t * 256;
    const int j = j0 + tid;
    float vals[8];
    if (j < TRIN) {
      // invert triangular index: largest i with S(i) <= j
      const float tt = 1999.0f;
      int i = (int)((tt - sqrtf(tt * tt - 8.0f * (float)j)) * 0.5f);
      i = max(0, min(i, 998));
      while (tri_S(i + 1) <= j) ++i;
      while (tri_S(i) > j) --i;
      int i1 = j - tri_S(i) + i + 1;
      size_t base = (size_t)i * FF + i1;
#pragma unroll
      for (int b = 0; b < 8; ++b) vals[b] = x[(size_t)b * (FF * NPP) + base];
      float m = 0.0f;
#pragma unroll
      for (int b = 0; b < 8; ++b) m += vals[b];
      m *= 0.125f;
      float va = 0.0f;
#pragma unroll
      for (int b = 0; b < 8; ++b) { float d = vals[b] - m; va += d * d; }
      va *= 0.125f;
      float sc = bng[j] * rsqrtf(va + EPSV);
      float tb = bnb[j] - m * sc;
#pragma unroll
      for (int b = 0; b < 8; ++b) vals[b] = sc * vals[b] + tb;
    } else {
#pragma unroll
      for (int b = 0; b < 8; ++b) vals[b] = 0.0f;
    }
    __syncthreads();
    *(float4*)&fbn_s[tid][0] = make_float4(vals[0], vals[1], vals[2], vals[3]);
    *(float4*)&fbn_s[tid][4] = make_float4(vals[4], vals[5], vals[6], vals[7]);
    __syncthreads();
    const int jbase = stripe * 32;
    if (j0 + 256 <= TRIN) {
#pragma unroll 8
      for (int jj = jbase; jj < jbase + 32; ++jj) {
        float4 w = *(const float4*)(W1 + (size_t)(j0 + jj) * HID + c4);
        float4 f0 = *(const float4*)&fbn_s[jj][0];
        float4 f1 = *(const float4*)&fbn_s[jj][4];
        float wv[4] = {w.x, w.y, w.z, w.w};
        float fv[8] = {f0.x, f0.y, f0.z, f0.w, f1.x, f1.y, f1.z, f1.w};
#pragma unroll
        for (int b = 0; b < 8; ++b)
#pragma unroll
          for (int q = 0; q < 4; ++q) acc[b][q] += fv[b] * wv[q];
      }
    } else {
      for (int jj = jbase; jj < jbase + 32; ++jj) {
        if (j0 + jj >= TRIN) break;
        float4 w = *(const float4*)(W1 + (size_t)(j0 + jj) * HID + c4);
        float4 f0 = *(const float4*)&fbn_s[jj][0];
        float4 f1 = *(const float4*)&fbn_s[jj][4];
        float wv[4] = {w.x, w.y, w.z, w.w};
        float fv[8] = {f0.x, f0.y, f0.z, f0.w, f1.x, f1.y, f1.z, f1.w};
#pragma unroll
        for (int b = 0; b < 8; ++b)
#pragma unroll
          for (int q = 0; q < 4; ++q) acc[b][q] += fv[b] * wv[q];
      }
    }
  }
  // stripe reduction in LDS, then one atomic per (b,col) per block,
  // spread over 8 accumulator replicas to de-serialize the atomic tail
#pragma unroll
  for (int b = 0; b < 8; ++b) {
    __syncthreads();
    red[stripe][c4 + 0] = acc[b][0];
    red[stripe][c4 + 1] = acc[b][1];
    red[stripe][c4 + 2] = acc[b][2];
    red[stripe][c4 + 3] = acc[b][3];
    __syncthreads();
    if (tid < 128) {
      float s = 0.0f;
#pragma unroll
      for (int q = 0; q < 8; ++q) s += red[q][tid];
      atomicAdd(&accrep[(blockIdx.x & 7) * 1024 + b * HID + tid], s);
    }
  }
}

// ---------------- MLP tail (+ hbn fused, + replica reduction) ----------------

__global__ void __launch_bounds__(128) k_mlp(
    const float* __restrict__ accrep, const float* __restrict__ emb,
    const float* __restrict__ hg, const float* __restrict__ hb,
    const float* __restrict__ mb1,
    const float* __restrict__ g1, const float* __restrict__ be1,
    const float* __restrict__ W2, const float* __restrict__ mb2,
    const float* __restrict__ g2, const float* __restrict__ be2,
    const float* __restrict__ W3, const float* __restrict__ mb3,
    const float* __restrict__ g3, const float* __restrict__ be3,
    const float* __restrict__ W4, const float* __restrict__ mb4,
    float* __restrict__ out) {
  __shared__ float A[8][128];
  __shared__ float Bm[8][64];
  __shared__ float Cm[8][64];
  __shared__ float lg[8][2];
  int tid = threadIdx.x;
  // hbn head (independent path, writes out[16:784])
  if (tid < 96) {
    float v[8];
    float m = 0.0f;
#pragma unroll
    for (int q = 0; q < 8; ++q) { v[q] = emb[q * 96 + tid]; m += v[q]; }
    m *= 0.125f;
    float va = 0.0f;
#pragma unroll
    for (int q = 0; q < 8; ++q) { float d = v[q] - m; va += d * d; }
    va *= 0.125f;
    float s = hg[tid] * rsqrtf(va + EPSV);
    float t = hb[tid] - m * s;
#pragma unroll
    for (int q = 0; q < 8; ++q) out[16 + q * 96 + tid] = s * v[q] + t;
  }
  // mlp layer 1: reduce 8 accumulator replicas, +bias, BN, relu
  {
    float v[8];
#pragma unroll
    for (int b = 0; b < 8; ++b) {
      float a = mb1[tid];
#pragma unroll
      for (int rep = 0; rep < 8; ++rep) a += accrep[rep * 1024 + b * HID + tid];
      v[b] = a;
    }
    float m = 0.0f;
#pragma unroll
    for (int b = 0; b < 8; ++b) m += v[b];
    m *= 0.125f;
    float va = 0.0f;
#pragma unroll
    for (int b = 0; b < 8; ++b) { float d = v[b] - m; va += d * d; }
    va *= 0.125f;
    float s = g1[tid] * rsqrtf(va + EPSV);
    float t = be1[tid] - m * s;
#pragma unroll
    for (int b = 0; b < 8; ++b) {
      float z = s * v[b] + t;
      A[b][tid] = (z > 0.0f) ? z : 0.0f;
    }
  }
  __syncthreads();
  if (tid < 64) {
    float v[8];
#pragma unroll
    for (int b = 0; b < 8; ++b) {
      float a2 = mb2[tid];
      for (int j = 0; j < 128; ++j) a2 += A[b][j] * W2[j * 64 + tid];
      v[b] = a2;
    }
    float m = 0.0f;
#pragma unroll
    for (int b = 0; b < 8; ++b) m += v[b];
    m *= 0.125f;
    float va = 0.0f;
#pragma unroll
    for (int b = 0; b < 8; ++b) { float d = v[b] - m; va += d * d; }
    va *= 0.125f;
    float s = g2[tid] * rsqrtf(va + EPSV);
    float t = be2[tid] - m * s;
#pragma unroll
    for (int b = 0; b < 8; ++b) {
      float z = s * v[b] + t;
      Bm[b][tid] = (z > 0.0f) ? z : 0.0f;
    }
  }
  __syncthreads();
  if (tid < 64) {
    float v[8];
#pragma unroll
    for (int b = 0; b < 8; ++b) {
      float a3 = mb3[tid];
      for (int j = 0; j < 64; ++j) a3 += Bm[b][j] * W3[j * 64 + tid];
      v[b] = a3;
    }
    float m = 0.0f;
#pragma unroll
    for (int b = 0; b < 8; ++b) m += v[b];
    m *= 0.125f;
    float va = 0.0f;
#pragma unroll
    for (int b = 0; b < 8; ++b) { float d = v[b] - m; va += d * d; }
    va *= 0.125f;
    float s = g3[tid] * rsqrtf(va + EPSV);
    float t = be3[tid] - m * s;
#pragma unroll
    for (int b = 0; b < 8; ++b) {
      float z = s * v[b] + t;
      Cm[b][tid] = (z > 0.0f) ? z : 0.0f;
    }
  }
  __syncthreads();
  if (tid < 16) {
    int b = tid >> 1, c = tid & 1;
    float a4 = mb4[c];
    for (int j = 0; j < 64; ++j) a4 += Cm[b][j] * W4[j * 2 + c];
    lg[b][c] = a4;
  }
  __syncthreads();
  if (tid < 8) {
    float l0 = lg[tid][0], l1 = lg[tid][1];
    float mm = fmaxf(l0, l1);
    float lse = mm + logf(expf(l0 - mm) + expf(l1 - mm));
    out[tid * 2 + 0] = l0 - lse;
    out[tid * 2 + 1] = l1 - lse;
  }
}

// ---------------- launch ----------------

extern "C" void kernel_launch(void* const* d_in, const int* in_sizes, int n_in,
                              void* d_out, int out_size, void* d_ws, size_t ws_size,
                              hipStream_t stream) {
  const float* x = (const float*)d_in[0];
  const int* ei = (const int*)d_in[1];
  const int* src = ei;
  const int* dst = ei + EE;
  const float* cw0 = (const float*)d_in[3];
  const float* cb0 = (const float*)d_in[4];
  const float* cw1 = (const float*)d_in[5];
  const float* cb1 = (const float*)d_in[6];
  const float* cw2 = (const float*)d_in[7];
  const float* cb2 = (const float*)d_in[8];
  const float* bnhg = (const float*)d_in[9];
  const float* bnhb = (const float*)d_in[10];
  const float* bng = (const float*)d_in[11];
  const float* bnb = (const float*)d_in[12];
  const float* mw1 = (const float*)d_in[13];
  const float* mb1 = (const float*)d_in[14];
  const float* b1g = (const float*)d_in[15];
  const float* b1b = (const float*)d_in[16];
  const float* mw2 = (const float*)d_in[17];
  const float* mb2 = (const float*)d_in[18];
  const float* b2g = (const float*)d_in[19];
  const float* b2b = (const float*)d_in[20];
  const float* mw3 = (const float*)d_in[21];
  const float* mb3 = (const float*)d_in[22];
  const float* b3g = (const float*)d_in[23];
  const float* b3b = (const float*)d_in[24];
  const float* mw4 = (const float*)d_in[25];
  const float* mb4 = (const float*)d_in[26];

  float* ws = (float*)d_ws;
  int* wsi = (int*)d_ws;
  float* out = (float*)d_out;

  hipMemsetAsync(wsi, 0, ZERO_N * sizeof(int), stream);

  // big memory-bound GEMM (longest single kernel)
  k_gemm1<<<976, 256, 0, stream>>>(x, bng, bnb, mw1, ws + IDX_ACC);

  k_count<<<(EE + 255) / 256, 256, 0, stream>>>(src, dst, wsi + IDX_DEGI, wsi + IDX_CNT);
  k_scan<<<1, 1024, 0, stream>>>(wsi + IDX_CNT, wsi + IDX_ROWS);
  k_fill<<<(EE + 255) / 256, 256, 0, stream>>>(src, dst, wsi + IDX_DEGI,
                                               wsi + IDX_ROWS, wsi + IDX_FILL,
                                               wsi + IDX_CSRC, ws + IDX_CSRW);

  float* ck = ws + IDX_CK;
  float* bA = ws + IDX_BA;
  float* bB = ws + IDX_BB;
  float* bC = ws + IDX_BC;
  float* emb = ws + IDX_EMB;
  const int* rows = wsi + IDX_ROWS;
  const int* csrc = wsi + IDX_CSRC;
  const float* csw = ws + IDX_CSRW;

  auto prop = [&](const float* in, int it, const float* prev, int pt,
                  const float* ckp, int ct, float* outp, float a, float b) {
    k_prop<<<NN / 8, 256, 0, stream>>>(in, it, prev, pt, ckp, ct, outp,
                                       rows, csrc, csw, a, b);
  };
  auto propf = [&](const float* in, const float* prev, const float* ckp, int ct,
                   const float* bias, const float* Wn, float* cko, int L) {
    k_prop_final<<<NN / 8, 256, 0, stream>>>(in, prev, ckp, ct, rows, csrc, csw,
                                             bias, Wn, cko, emb, L);
  };

  const int WS0 = NPP * HCC;  // 32000: stride of one W0[k] slab
  // layer 1 — Clenshaw with tiled W0 coefficients (no materialization)
  prop(cw0 + 4 * WS0, 1, nullptr, 0, cw0 + 3 * WS0, 1, bA, 2.0f, 0.0f);
  prop(bA, 0, cw0 + 4 * WS0, 1, cw0 + 2 * WS0, 1, bB, 2.0f, -1.0f);
  prop(bB, 0, bA, 0, cw0 + 1 * WS0, 1, bC, 2.0f, -1.0f);
  propf(bC, bB, cw0, 1, cb0, cw1, ck, 0);

  // layer 2
  prop(ck + 4 * CKSTRIDE, 0, nullptr, 0, ck + 3 * CKSTRIDE, 0, bA, 2.0f, 0.0f);
  prop(bA, 0, ck + 4 * CKSTRIDE, 0, ck + 2 * CKSTRIDE, 0, bB, 2.0f, -1.0f);
  prop(bB, 0, bA, 0, ck + 1 * CKSTRIDE, 0, bC, 2.0f, -1.0f);
  propf(bC, bB, ck, 0, cb1, cw2, ck, 1);

  // layer 3 (no next-layer coefficients)
  prop(ck + 4 * CKSTRIDE, 0, nullptr, 0, ck + 3 * CKSTRIDE, 0, bA, 2.0f, 0.0f);
  prop(bA, 0, ck + 4 * CKSTRIDE, 0, ck + 2 * CKSTRIDE, 0, bB, 2.0f, -1.0f);
  prop(bB, 0, bA, 0, ck + 1 * CKSTRIDE, 0, bC, 2.0f, -1.0f);
  propf(bC, bB, ck, 0, cb2, nullptr, nullptr, 2);

  k_mlp<<<1, 128, 0, stream>>>(ws + IDX_ACC, emb, bnhg, bnhb, mb1, b1g, b1b,
                               mw2, mb2, b2g, b2b, mw3, mb3, b3g, b3b,
                               mw4, mb4, out);
}